// Round 14
// baseline (883.506 us; speedup 1.0000x reference)
//
#include <hip/hip_runtime.h>

// ---------------- problem constants ----------------
#define NE 8          // experts
#define CAP 5120      // capacity (static: int(1.25*16384*2/8))
#define NT 16384      // tokens (B*T)
#define CD 1024       // channel dim C
#define FCD 4096      // 4*C

typedef __attribute__((ext_vector_type(8))) short short8;
typedef __attribute__((ext_vector_type(4))) float f32x4;

__device__ __forceinline__ unsigned short f2bf(float f) {
  unsigned int u = __builtin_bit_cast(unsigned int, f);
  u += 0x7FFFu + ((u >> 16) & 1u);   // RNE
  return (unsigned short)(u >> 16);
}
__device__ __forceinline__ float bf2f(unsigned short u) {
  unsigned int v = ((unsigned int)u) << 16;
  return __builtin_bit_cast(float, v);
}
// async global->LDS, 16B per lane. LDS dest wave-uniform base (+lane*16 implicit).
__device__ __forceinline__ void g2lds16(const unsigned short* g, unsigned short* l) {
  __builtin_amdgcn_global_load_lds(
      (const __attribute__((address_space(1))) unsigned int*)(unsigned long long)g,
      (__attribute__((address_space(3))) unsigned int*)l,
      16, 0, 0);
}

// ---------------- fills ----------------
__global__ __launch_bounds__(256) void fill_i32_k(int* __restrict__ p, int v, int n) {
  int i = blockIdx.x * 256 + threadIdx.x;
  if (i < n) p[i] = v;
}
__global__ __launch_bounds__(256) void fill_zero_f32x4_k(float4* __restrict__ p, size_t n4) {
  size_t i = (size_t)blockIdx.x * 256 + threadIdx.x;
  if (i < n4) p[i] = make_float4(0.f, 0.f, 0.f, 0.f);
}

// ---------------- transpose + fp32->bf16 (weights) ----------------
__global__ __launch_bounds__(256) void transpose_bf16_k(
    const float* __restrict__ in, unsigned short* __restrict__ out, int R, int Cc) {
  __shared__ float tile[64][65];
  const size_t esz = (size_t)R * Cc;
  const float* inp = in + (size_t)blockIdx.z * esz;
  unsigned short* outp = out + (size_t)blockIdx.z * esz;
  const int cbase = blockIdx.x * 64, rbase = blockIdx.y * 64;
  const int t = threadIdx.x;
#pragma unroll
  for (int i = 0; i < 4; ++i) {
    int idx = i * 256 + t;
    int r = idx >> 4, c4 = (idx & 15) * 4;
    const float4 v = *reinterpret_cast<const float4*>(inp + (size_t)(rbase + r) * Cc + cbase + c4);
    tile[r][c4 + 0] = v.x; tile[r][c4 + 1] = v.y; tile[r][c4 + 2] = v.z; tile[r][c4 + 3] = v.w;
  }
  __syncthreads();
#pragma unroll
  for (int i = 0; i < 4; ++i) {
    int idx = i * 256 + t;
    int oc = idx >> 4, q = (idx & 15) * 4;
    ushort4 o;
    o.x = f2bf(tile[q + 0][oc]); o.y = f2bf(tile[q + 1][oc]);
    o.z = f2bf(tile[q + 2][oc]); o.w = f2bf(tile[q + 3][oc]);
    *reinterpret_cast<ushort4*>(outp + (size_t)(cbase + oc) * R + rbase + q) = o;
  }
}

// ---------------- router: fp64 logits, top-2, softmax; also x -> bf16 ----------------
__global__ __launch_bounds__(256) void router_k(
    const float* __restrict__ x, const float* __restrict__ wg,
    unsigned short* __restrict__ xb, int* __restrict__ topidx, float* __restrict__ probs) {
  __shared__ float wls[NE * CD];
  const int t = threadIdx.x;
  {
    const float4* w4 = (const float4*)wg;
    float4* l4 = (float4*)wls;
    for (int i = t; i < NE * CD / 4; i += 256) l4[i] = w4[i];
  }
  __syncthreads();
  const int wave = t >> 6, lane = t & 63;
  const int gw = blockIdx.x * 4 + wave;
  const float4* wls4 = (const float4*)wls;
#pragma unroll
  for (int it = 0; it < 2; ++it) {
    const int n = gw * 2 + it;
    const float4* xr4 = (const float4*)(x + (size_t)n * CD);
    ushort4* xb4 = (ushort4*)(xb + (size_t)n * CD);
    double acc[NE] = {0, 0, 0, 0, 0, 0, 0, 0};
#pragma unroll
    for (int j = 0; j < 4; ++j) {
      const int idx = j * 64 + lane;
      const float4 xv = xr4[idx];
      ushort4 o;
      o.x = f2bf(xv.x); o.y = f2bf(xv.y); o.z = f2bf(xv.z); o.w = f2bf(xv.w);
      xb4[idx] = o;
#pragma unroll
      for (int e = 0; e < NE; ++e) {
        const float4 wv = wls4[e * 256 + idx];
        acc[e] += (double)xv.x * (double)wv.x + (double)xv.y * (double)wv.y
                + (double)xv.z * (double)wv.z + (double)xv.w * (double)wv.w;
      }
    }
#pragma unroll
    for (int s = 32; s >= 1; s >>= 1) {
#pragma unroll
      for (int e = 0; e < NE; ++e) acc[e] += __shfl_xor(acc[e], s, 64);
    }
    if (lane == 0) {
      int i1 = 0; double v1 = acc[0];
      for (int e = 1; e < NE; ++e) if (acc[e] > v1) { v1 = acc[e]; i1 = e; }
      int i2 = -1; double v2 = -1e300;
      for (int e = 0; e < NE; ++e) if (e != i1 && acc[e] > v2) { v2 = acc[e]; i2 = e; }
      float p0 = 1.0f / (1.0f + expf((float)(v2 - v1)));
      topidx[n * 2 + 0] = i1; topidx[n * 2 + 1] = i2;
      probs[n * 2 + 0] = p0; probs[n * 2 + 1] = 1.0f - p0;
    }
  }
}

// ---------------- per-block expert histograms ----------------
__global__ __launch_bounds__(256) void hist_k(const int* __restrict__ topidx, int* __restrict__ blkhist) {
  __shared__ int h[16];
  const int t = threadIdx.x;
  if (t < 16) h[t] = 0;
  __syncthreads();
  const int n = blockIdx.x * 256 + t;
  atomicAdd(&h[topidx[n * 2 + 0]], 1);
  atomicAdd(&h[8 + topidx[n * 2 + 1]], 1);
  __syncthreads();
  if (t < 16) blkhist[blockIdx.x * 16 + t] = h[t];
}

// ---------------- scan ----------------
__global__ void scan_k(const int* __restrict__ blkhist, int* __restrict__ blkoff, int* __restrict__ totals_cnt) {
  const int t = threadIdx.x;
  if (t < 16) {
    int s = 0;
    for (int b = 0; b < 64; ++b) { blkoff[b * 16 + t] = s; s += blkhist[b * 16 + t]; }
    totals_cnt[t] = s;
  }
  __syncthreads();
  if (t < 8) {
    int tot = totals_cnt[t] + totals_cnt[8 + t];
    totals_cnt[16 + t] = tot < CAP ? tot : CAP;
  }
}

// ---------------- ranks + slot_map scatter (slotmap[e][rank] = n*2+k) ----------------
__global__ __launch_bounds__(256) void rank_k(
    const int* __restrict__ topidx, const int* __restrict__ blkoff,
    const int* __restrict__ totals_cnt, int* __restrict__ ranks, int* __restrict__ slotmap) {
  __shared__ int wcnt[2][4][8];
  __shared__ int woff[2][4][8];
  const int t = threadIdx.x, wave = t >> 6, lane = t & 63;
  const int n = blockIdx.x * 256 + t;
  const int e1 = topidx[n * 2 + 0], e2 = topidx[n * 2 + 1];
  const unsigned long long lt = (1ull << lane) - 1ull;
  int pre1 = 0, pre2 = 0;
#pragma unroll
  for (int e = 0; e < 8; ++e) {
    unsigned long long m1 = __ballot(e1 == e);
    unsigned long long m2 = __ballot(e2 == e);
    if (e1 == e) pre1 = __popcll(m1 & lt);
    if (e2 == e) pre2 = __popcll(m2 & lt);
    if (lane == 0) { wcnt[0][wave][e] = __popcll(m1); wcnt[1][wave][e] = __popcll(m2); }
  }
  __syncthreads();
  if (t < 16) {
    int k = t >> 3, e = t & 7, s = 0;
    for (int w = 0; w < 4; ++w) { woff[k][w][e] = s; s += wcnt[k][w][e]; }
  }
  __syncthreads();
  int r1 = blkoff[blockIdx.x * 16 + e1] + woff[0][wave][e1] + pre1;
  int r2 = totals_cnt[e2] + blkoff[blockIdx.x * 16 + 8 + e2] + woff[1][wave][e2] + pre2;
  ranks[n * 2 + 0] = (r1 < CAP) ? r1 : -1;
  ranks[n * 2 + 1] = (r2 < CAP) ? r2 : -1;
  if (r1 < CAP) slotmap[e1 * CAP + r1] = n * 2 + 0;
  if (r2 < CAP) slotmap[e2 * CAP + r2] = n * 2 + 1;
}

// ---- shared mapping helper: live-tile compaction + chunked-XCD, nt fastest ----
template <int BM, int TN>
__device__ __forceinline__ bool map_tile(const int* cnt, int e_base, int n_le,
                                         int& le, int& mt, int& nt) {
  constexpr int TM = CAP / BM;
  int pref[9];
  int L = 0;
  for (int i = 0; i < n_le; ++i) {
    pref[i] = L;
    int lm = (cnt[e_base + i] + BM - 1) / BM;
    if (lm > TM) lm = TM;
    L += lm;
  }
  const int totalLive = L * TN;
  const int bid = blockIdx.x;
  if (bid >= totalLive) return false;
  const int q = totalLive >> 3, r = totalLive & 7;
  const int xcd = bid & 7, lin = bid >> 3;
  const int wid = (xcd < r ? xcd * (q + 1) : r * (q + 1) + (xcd - r) * q) + lin;
  const int pair = wid / TN;
  nt = wid % TN;                   // nt fastest: siblings share A-panel in XCD L2
  le = n_le - 1;
  for (int i = 1; i < n_le; ++i) if (pair < pref[i]) { le = i - 1; break; }
  mt = pair - pref[le];
  return true;
}

// ====== G1: 4-phase MFMA GEMM, BK=64, 2-slot dbuf, counted vmcnt, T2 swizzle ======
// R13 ledger (24 ds_read_b128/wave/tile): quadrants (0,0)->(0,1)->(1,1)->(1,0);
// B0 frags held in regs across the tile. Proven R13 (873us run).
template <int BM, int KDIM, int NDIM, bool GATHER, bool RELU2>
__global__ __launch_bounds__(512) void gemm8p_k(
    const unsigned short* __restrict__ A, const unsigned short* __restrict__ Bt,
    unsigned short* __restrict__ Out, const int* __restrict__ slotmap,
    const int* __restrict__ cnt, int e_base, int n_le) {
  constexpr int BN = 256;
  constexpr int KT = KDIM / 64;
  constexpr int TN = NDIM / BN;
  constexpr int M_REP = BM / 32;
  constexpr int QM = M_REP / 2;
  constexpr int AL = BM / 128;
  constexpr int BL = 2;
  constexpr int V = AL + BL;

  __shared__ unsigned short lA[2][BM * 64];
  __shared__ unsigned short lB[2][BN * 64];

  int le, mt, nt;
  if (!map_tile<BM, TN>(cnt, e_base, n_le, le, mt, nt)) return;
  const int e = e_base + le;

  const int tid = threadIdx.x;
  const int wave = tid >> 6, lane = tid & 63;
  const int wr = wave >> 2, wc = wave & 3;
  const int l15 = lane & 15, l4 = lane >> 4;

  const unsigned short* sApt[2][AL];
  const unsigned short* sBpt[2][BL];
#pragma unroll
  for (int h = 0; h < 2; ++h) {
#pragma unroll
    for (int j = 0; j < AL; ++j) {
      const int lc = j * 512 + tid;
      const int lr = lc >> 3, pc = lc & 7;
      const int logc = pc ^ (lr & 7);
      const int rowT = h * (BM / 2) + lr;
      size_t grow;
      if (GATHER) {
        const int sv = slotmap[e * CAP + mt * BM + rowT];
        grow = (size_t)(sv < 0 ? 0 : (sv >> 1));
      } else {
        grow = (size_t)le * CAP + mt * BM + rowT;
      }
      sApt[h][j] = A + grow * KDIM + logc * 8;
    }
#pragma unroll
    for (int j = 0; j < BL; ++j) {
      const int lc = j * 512 + tid;
      const int lr = lc >> 3, pc = lc & 7;
      const int logc = pc ^ (lr & 7);
      sBpt[h][j] = Bt + ((size_t)le * NDIM + nt * BN + h * 128 + lr) * KDIM + logc * 8;
    }
  }

#define STAGE_A(sl, h, tt)                                                              \
  do { _Pragma("unroll") for (int j = 0; j < AL; ++j)                                   \
    g2lds16(sApt[h][j] + (size_t)(tt) * 64,                                             \
            &lA[sl][((h) * (BM / 2) * 8 + j * 512 + wave * 64) * 8]); } while (0)
#define STAGE_B(sl, h, tt)                                                              \
  do { _Pragma("unroll") for (int j = 0; j < BL; ++j)                                   \
    g2lds16(sBpt[h][j] + (size_t)(tt) * 64,                                             \
            &lB[sl][((h) * 128 * 8 + j * 512 + wave * 64) * 8]); } while (0)

  const int kidx0 = ((0 * 4 + l4) ^ (l15 & 7)) * 8;
  const int kidx1 = ((1 * 4 + l4) ^ (l15 & 7)) * 8;

#define RD_A(mh)                                                                        \
  do { _Pragma("unroll") for (int m = 0; m < QM; ++m) {                                 \
    const int row = (mh) * (BM / 2) + wr * (BM / 4) + m * 16 + l15;                     \
    aF[m][0] = *(const short8*)(bA + row * 64 + kidx0);                                 \
    aF[m][1] = *(const short8*)(bA + row * 64 + kidx1); } } while (0)
#define RD_B(DST, nh)                                                                   \
  do { _Pragma("unroll") for (int n = 0; n < 2; ++n) {                                  \
    const int row = (nh) * 128 + wc * 32 + n * 16 + l15;                                \
    DST[n][0] = *(const short8*)(bB + row * 64 + kidx0);                                \
    DST[n][1] = *(const short8*)(bB + row * 64 + kidx1); } } while (0)
#define LGK0()                                                                          \
  do { asm volatile("s_waitcnt lgkmcnt(0)" ::: "memory");                               \
       __builtin_amdgcn_sched_barrier(0); } while (0)
#define MF(BARR, mh, nh)                                                                \
  do { __builtin_amdgcn_s_setprio(1);                                                   \
    _Pragma("unroll") for (int m = 0; m < QM; ++m)                                      \
      _Pragma("unroll") for (int n = 0; n < 2; ++n) {                                   \
        acc[(mh) * QM + m][(nh) * 2 + n] = __builtin_amdgcn_mfma_f32_16x16x32_bf16(     \
            aF[m][0], BARR[n][0], acc[(mh) * QM + m][(nh) * 2 + n], 0, 0, 0);           \
        acc[(mh) * QM + m][(nh) * 2 + n] = __builtin_amdgcn_mfma_f32_16x16x32_bf16(     \
            aF[m][1], BARR[n][1], acc[(mh) * QM + m][(nh) * 2 + n], 0, 0, 0); }         \
    __builtin_amdgcn_s_setprio(0); } while (0)
#define VMC_V()  do { if constexpr (V == 4) asm volatile("s_waitcnt vmcnt(4)" ::: "memory"); \
                      else asm volatile("s_waitcnt vmcnt(3)" ::: "memory"); } while (0)
#define VMC_2()  asm volatile("s_waitcnt vmcnt(2)" ::: "memory")
#define VMC_0()  asm volatile("s_waitcnt vmcnt(0)" ::: "memory")
#define BAR()    do { __builtin_amdgcn_s_barrier(); asm volatile("" ::: "memory"); } while (0)

  f32x4 acc[M_REP][4] = {};
  short8 aF[QM][2], bF0[2][2], bF1[2][2];

  STAGE_A(0, 0, 0); STAGE_B(0, 0, 0); STAGE_B(0, 1, 0); STAGE_A(0, 1, 0);
  VMC_V();
  BAR();

  int s = 0;
  for (int t = 0; t < KT; ++t) {
    const int s2 = s ^ 1;
    const unsigned short* bA = &lA[s][0];
    const unsigned short* bB = &lB[s][0];
    const bool more = (t + 1 < KT);

    RD_A(0); RD_B(bF0, 0);
    if (more) { STAGE_A(s2, 0, t + 1); VMC_V(); } else { VMC_2(); }
    LGK0();
    MF(bF0, 0, 0);
    BAR();
    RD_B(bF1, 1);
    if (more) { STAGE_B(s2, 0, t + 1); VMC_V(); } else { VMC_0(); }
    LGK0();
    MF(bF1, 0, 1);
    BAR();
    RD_A(1);
    if (more) STAGE_B(s2, 1, t + 1);
    LGK0();
    MF(bF1, 1, 1);
    if (more) { STAGE_A(s2, 1, t + 1); VMC_V(); }
    MF(bF0, 1, 0);
    if (more) BAR();
    s = s2;
  }

  const size_t rowb = (size_t)le * CAP + mt * BM;
  const int colb = nt * BN;
#pragma unroll
  for (int i = 0; i < M_REP; ++i) {
    const int mh = i / QM, m = i % QM;
#pragma unroll
    for (int j = 0; j < 4; ++j) {
      const int nh = j / 2, n = j % 2;
#pragma unroll
      for (int rr = 0; rr < 4; ++rr) {
        float v = acc[i][j][rr];
        if (RELU2) { v = fmaxf(v, 0.0f); v = v * v; }
        const size_t orow = rowb + mh * (BM / 2) + wr * (BM / 4) + m * 16 + l4 * 4 + rr;
        Out[orow * NDIM + colb + nh * 128 + wc * 32 + n * 16 + l15] = f2bf(v);
      }
    }
  }
#undef STAGE_A
#undef STAGE_B
#undef RD_A
#undef RD_B
#undef LGK0
#undef MF
#undef VMC_V
#undef VMC_2
#undef VMC_0
#undef BAR
}

// ====== G2: pipelined MFMA GEMM (R5/R11-proven): BK=32, 3-slot LDS, counted vmcnt ======
// SCATTER epilogue (R14): out[token] += prob * acc via atomicAdd f32 (a token's two
// experts can be in the SAME dispatch -> non-atomic RMW races; atomics required).
// Each out element receives exactly 2 adds total -> ordering noise << threshold.
template <int WM, int WN, int BM, int BN, int KDIM, int NDIM, bool GATHER, bool RELU2, bool SCATTER>
__global__ __launch_bounds__(WM * WN * 64) void gemm8_k(
    const unsigned short* __restrict__ A, const unsigned short* __restrict__ Bt,
    unsigned short* __restrict__ Out, const int* __restrict__ slotmap,
    const int* __restrict__ cnt, int e_base, int n_le,
    const float* __restrict__ probs, float* __restrict__ outp) {
  constexpr int THREADS = WM * WN * 64;
  constexpr int KT = KDIM / 32;
  constexpr int TN = NDIM / BN;
  constexpr int M_REP = BM / WM / 16;
  constexpr int N_REP = BN / WN / 16;
  constexpr int MH = M_REP / 2;
  constexpr int ALOADS = BM * 4 / THREADS;
  constexpr int BLOADS = BN * 4 / THREADS;
  static_assert(ALOADS + BLOADS == 4, "vmcnt literal assumes 4 loads/wave/tile");

  __shared__ unsigned short lA[3][BM * 32];
  __shared__ unsigned short lB[3][BN * 32];

  int le, mt, nt;
  if (!map_tile<BM, TN>(cnt, e_base, n_le, le, mt, nt)) return;
  const int e = e_base + le;

  const int tid = threadIdx.x;
  const int wave = tid >> 6, lane = tid & 63;
  const int wr = wave / WN, wc = wave % WN;
  const int l15 = lane & 15, l4 = lane >> 4;

  const unsigned short* pA[ALOADS];
  const unsigned short* pB[BLOADS];
#pragma unroll
  for (int j = 0; j < ALOADS; ++j) {
    const int ci = j * THREADS + tid;
    const int row = ci >> 2, cst = ci & 3;
    const int csrc = cst ^ ((row >> 1) & 3);
    size_t grow;
    if (GATHER) {
      const int sv = slotmap[e * CAP + mt * BM + row];
      grow = (size_t)(sv < 0 ? 0 : (sv >> 1));
    } else {
      grow = (size_t)le * CAP + mt * BM + row;
    }
    pA[j] = A + grow * KDIM + csrc * 8;
  }
#pragma unroll
  for (int j = 0; j < BLOADS; ++j) {
    const int ci = j * THREADS + tid;
    const int row = ci >> 2, cst = ci & 3;
    const int csrc = cst ^ ((row >> 1) & 3);
    pB[j] = Bt + ((size_t)le * NDIM + nt * BN + row) * KDIM + csrc * 8;
  }

  const int ksw = (l4 ^ ((l15 >> 1) & 3)) * 8;
  int aOff[M_REP], bOff[N_REP];
#pragma unroll
  for (int m = 0; m < M_REP; ++m)
    aOff[m] = (wr * (BM / WM) + m * 16 + l15) * 32 + ksw;
#pragma unroll
  for (int n = 0; n < N_REP; ++n)
    bOff[n] = (wc * (BN / WN) + n * 16 + l15) * 32 + ksw;

  f32x4 acc[M_REP][N_REP] = {};

#pragma unroll
  for (int kt = 0; kt < 2; ++kt) {
#pragma unroll
    for (int j = 0; j < ALOADS; ++j)
      g2lds16(pA[j] + kt * 32, &lA[kt][(j * THREADS + wave * 64) * 8]);
#pragma unroll
    for (int j = 0; j < BLOADS; ++j)
      g2lds16(pB[j] + kt * 32, &lB[kt][(j * THREADS + wave * 64) * 8]);
  }

  for (int t = 0; t < KT; ++t) {
    if (t < KT - 1) asm volatile("s_waitcnt vmcnt(4)" ::: "memory");
    else            asm volatile("s_waitcnt vmcnt(0)" ::: "memory");
    __builtin_amdgcn_s_barrier();
    asm volatile("" ::: "memory");

    const int s = t % 3, s2 = (t + 2) % 3;
    const unsigned short* sA = &lA[s][0];
    const unsigned short* sB = &lB[s][0];
    const bool pf = (t + 2 < KT);

    short8 aF[MH], bF[N_REP];
#pragma unroll
    for (int m = 0; m < MH; ++m) aF[m] = *(const short8*)(sA + aOff[m]);
#pragma unroll
    for (int n = 0; n < N_REP; ++n) bF[n] = *(const short8*)(sB + bOff[n]);
    if (pf) {
#pragma unroll
      for (int j = 0; j < ALOADS; ++j)
        g2lds16(pA[j] + (t + 2) * 32, &lA[s2][(j * THREADS + wave * 64) * 8]);
    }
    asm volatile("s_waitcnt lgkmcnt(0)" ::: "memory");
    __builtin_amdgcn_sched_barrier(0);
    __builtin_amdgcn_s_setprio(1);
#pragma unroll
    for (int m = 0; m < MH; ++m)
#pragma unroll
      for (int n = 0; n < N_REP; ++n)
        acc[m][n] = __builtin_amdgcn_mfma_f32_16x16x32_bf16(aF[m], bF[n], acc[m][n], 0, 0, 0);
    __builtin_amdgcn_s_setprio(0);

    short8 aG[MH];
#pragma unroll
    for (int m = 0; m < MH; ++m) aG[m] = *(const short8*)(sA + aOff[MH + m]);
    if (pf) {
#pragma unroll
      for (int j = 0; j < BLOADS; ++j)
        g2lds16(pB[j] + (t + 2) * 32, &lB[s2][(j * THREADS + wave * 64) * 8]);
    }
    asm volatile("s_waitcnt lgkmcnt(0)" ::: "memory");
    __builtin_amdgcn_sched_barrier(0);
    __builtin_amdgcn_s_setprio(1);
#pragma unroll
    for (int m = 0; m < MH; ++m)
#pragma unroll
      for (int n = 0; n < N_REP; ++n)
        acc[MH + m][n] = __builtin_amdgcn_mfma_f32_16x16x32_bf16(aG[m], bF[n], acc[MH + m][n], 0, 0, 0);
    __builtin_amdgcn_s_setprio(0);
  }

  if (SCATTER) {
    const int colb = nt * BN + wc * (BN / WN);
#pragma unroll
    for (int m = 0; m < M_REP; ++m) {
#pragma unroll
      for (int rr = 0; rr < 4; ++rr) {
        const int rl = mt * BM + wr * (BM / WM) + m * 16 + l4 * 4 + rr;
        const int sv = slotmap[e * CAP + rl];
        if (sv < 0) continue;
        const float p = probs[sv];
        float* ob = outp + (size_t)(sv >> 1) * CD + colb + l15;
#pragma unroll
        for (int n = 0; n < N_REP; ++n)
          atomicAdd(&ob[n * 16], p * acc[m][n][rr]);
      }
    }
  } else {
    const size_t rowb = (size_t)le * CAP + mt * BM + wr * (BM / WM);
    const int colb = nt * BN + wc * (BN / WN);
#pragma unroll
    for (int m = 0; m < M_REP; ++m)
#pragma unroll
      for (int n = 0; n < N_REP; ++n)
#pragma unroll
        for (int rr = 0; rr < 4; ++rr) {
          float v = acc[m][n][rr];
          if (RELU2) { v = fmaxf(v, 0.0f); v = v * v; }
          Out[(rowb + m * 16 + l4 * 4 + rr) * NDIM + colb + n * 16 + l15] = f2bf(v);
        }
  }
}

// ---------------- launch ----------------
extern "C" void kernel_launch(void* const* d_in, const int* in_sizes, int n_in,
                              void* d_out, int out_size, void* d_ws, size_t ws_size,
                              hipStream_t stream) {
  const float* x = (const float*)d_in[0];
  const float* wg = (const float*)d_in[1];
  const float* cfc = (const float*)d_in[2];
  const float* cproj = (const float*)d_in[3];
  float* out = (float*)d_out;
  char* ws = (char*)d_ws;
  (void)in_sizes; (void)n_in; (void)out_size;

  const size_t W1SZ = (size_t)FCD * CD * 2;    // 8 MB per expert weight (bf16, transposed)
  const size_t HSZ  = (size_t)CAP * FCD * 2;   // 40 MB per expert hidden

  size_t off = 0;
  auto alloc = [&](size_t bytes) { size_t o = off; off = (off + bytes + 255) & ~(size_t)255; return o; };
  unsigned short* XB = (unsigned short*)(ws + alloc((size_t)NT * CD * 2));   // 32 MB
  int* TOPIDX  = (int*)(ws + alloc((size_t)NT * 2 * 4));
  float* PROBS = (float*)(ws + alloc((size_t)NT * 2 * 4));
  int* RANKS   = (int*)(ws + alloc((size_t)NT * 2 * 4));
  int* SLOTMAP = (int*)(ws + alloc((size_t)NE * CAP * 4));
  int* BLKHIST = (int*)(ws + alloc(64 * 16 * 4));
  int* BLKOFF  = (int*)(ws + alloc(64 * 16 * 4));
  int* TOTALS  = (int*)(ws + alloc(256));
  const size_t shared_end = off;
  int* CNT = TOTALS + 16;

  size_t woff = shared_end;
  auto walloc = [&](size_t bytes) { size_t o = woff; woff = (woff + bytes + 255) & ~(size_t)255; return o; };
  const size_t oCFCT   = walloc(NE * W1SZ);   // 64 MB
  const size_t oCPROJT = walloc(NE * W1SZ);   // 64 MB
  const size_t weights_end = woff;

  // pick largest EG in {8,4,2,1}: weights + EG*H (EO eliminated via fused scatter-G2)
  int EG = 0;
  for (int g = 8; g >= 1; g >>= 1) {
    size_t need = weights_end + (size_t)g * HSZ + 512;
    if (ws_size >= need) { EG = g; break; }
  }
  if (EG == 0) {
    fill_zero_f32x4_k<<<(NT * CD / 4 + 255) / 256, 256, 0, stream>>>((float4*)out, (size_t)NT * CD / 4);
    return;   // controlled failure instead of memory fault
  }

  // prologue
  fill_i32_k<<<(NE * CAP + 255) / 256, 256, 0, stream>>>(SLOTMAP, -1, NE * CAP);
  fill_zero_f32x4_k<<<(NT * CD / 4 + 255) / 256, 256, 0, stream>>>((float4*)out, (size_t)NT * CD / 4);
  router_k<<<2048, 256, 0, stream>>>(x, wg, XB, TOPIDX, PROBS);
  hist_k<<<64, 256, 0, stream>>>(TOPIDX, BLKHIST);
  scan_k<<<1, 64, 0, stream>>>(BLKHIST, BLKOFF, TOTALS);
  rank_k<<<64, 256, 0, stream>>>(TOPIDX, BLKOFF, TOTALS, RANKS, SLOTMAP);

  unsigned short* CFCT   = (unsigned short*)(ws + oCFCT);
  unsigned short* CPROJT = (unsigned short*)(ws + oCPROJT);
  transpose_bf16_k<<<dim3(FCD / 64, CD / 64, NE), 256, 0, stream>>>(cfc, CFCT, CD, FCD);
  transpose_bf16_k<<<dim3(CD / 64, FCD / 64, NE), 256, 0, stream>>>(cproj, CPROJT, FCD, CD);

  unsigned short* H = (unsigned short*)(ws + weights_end);

  for (int g = 0; g < NE / EG; ++g) {
    const int eb = g * EG;
    // G1: 256x256, 8 waves, 4-phase pipeline (R13 ledger) + compaction
    gemm8p_k<256, CD, FCD, true, true>
        <<<EG * (CAP / 256) * (FCD / 256), 512, 0, stream>>>(
        XB, CFCT + (size_t)eb * FCD * CD, H, SLOTMAP, CNT, eb, EG);
    // G2: 128x128, 4 waves, 3-slot BK32, 3 blocks/CU + compaction + fused scatter-combine
    gemm8_k<2, 2, 128, 128, FCD, CD, false, false, true>
        <<<EG * (CAP / 128) * (CD / 128), 256, 0, stream>>>(
        H, CPROJT + (size_t)eb * CD * FCD, nullptr, SLOTMAP, CNT, eb, EG, PROBS, out);
  }
}

// Round 15
// 849.108 us; speedup vs baseline: 1.0405x; 1.0405x over previous
//
#include <hip/hip_runtime.h>

// ---------------- problem constants ----------------
#define NE 8          // experts
#define CAP 5120      // capacity (static: int(1.25*16384*2/8))
#define NT 16384      // tokens (B*T)
#define CD 1024       // channel dim C
#define FCD 4096      // 4*C

typedef __attribute__((ext_vector_type(8))) short short8;
typedef __attribute__((ext_vector_type(4))) float f32x4;

__device__ __forceinline__ unsigned short f2bf(float f) {
  unsigned int u = __builtin_bit_cast(unsigned int, f);
  u += 0x7FFFu + ((u >> 16) & 1u);   // RNE
  return (unsigned short)(u >> 16);
}
__device__ __forceinline__ float bf2f(unsigned short u) {
  unsigned int v = ((unsigned int)u) << 16;
  return __builtin_bit_cast(float, v);
}
// async global->LDS, 16B per lane. LDS dest wave-uniform base (+lane*16 implicit).
__device__ __forceinline__ void g2lds16(const unsigned short* g, unsigned short* l) {
  __builtin_amdgcn_global_load_lds(
      (const __attribute__((address_space(1))) unsigned int*)(unsigned long long)g,
      (__attribute__((address_space(3))) unsigned int*)l,
      16, 0, 0);
}

// ---------------- fills ----------------
__global__ __launch_bounds__(256) void fill_i32_k(int* __restrict__ p, int v, int n) {
  int i = blockIdx.x * 256 + threadIdx.x;
  if (i < n) p[i] = v;
}
__global__ __launch_bounds__(256) void fill_zero_f32x4_k(float4* __restrict__ p, size_t n4) {
  size_t i = (size_t)blockIdx.x * 256 + threadIdx.x;
  if (i < n4) p[i] = make_float4(0.f, 0.f, 0.f, 0.f);
}

// ---------------- transpose + fp32->bf16 (weights) ----------------
__global__ __launch_bounds__(256) void transpose_bf16_k(
    const float* __restrict__ in, unsigned short* __restrict__ out, int R, int Cc) {
  __shared__ float tile[64][65];
  const size_t esz = (size_t)R * Cc;
  const float* inp = in + (size_t)blockIdx.z * esz;
  unsigned short* outp = out + (size_t)blockIdx.z * esz;
  const int cbase = blockIdx.x * 64, rbase = blockIdx.y * 64;
  const int t = threadIdx.x;
#pragma unroll
  for (int i = 0; i < 4; ++i) {
    int idx = i * 256 + t;
    int r = idx >> 4, c4 = (idx & 15) * 4;
    const float4 v = *reinterpret_cast<const float4*>(inp + (size_t)(rbase + r) * Cc + cbase + c4);
    tile[r][c4 + 0] = v.x; tile[r][c4 + 1] = v.y; tile[r][c4 + 2] = v.z; tile[r][c4 + 3] = v.w;
  }
  __syncthreads();
#pragma unroll
  for (int i = 0; i < 4; ++i) {
    int idx = i * 256 + t;
    int oc = idx >> 4, q = (idx & 15) * 4;
    ushort4 o;
    o.x = f2bf(tile[q + 0][oc]); o.y = f2bf(tile[q + 1][oc]);
    o.z = f2bf(tile[q + 2][oc]); o.w = f2bf(tile[q + 3][oc]);
    *reinterpret_cast<ushort4*>(outp + (size_t)(cbase + oc) * R + rbase + q) = o;
  }
}

// ---------------- router: fp64 logits, top-2, softmax; also x -> bf16 ----------------
__global__ __launch_bounds__(256) void router_k(
    const float* __restrict__ x, const float* __restrict__ wg,
    unsigned short* __restrict__ xb, int* __restrict__ topidx, float* __restrict__ probs) {
  __shared__ float wls[NE * CD];
  const int t = threadIdx.x;
  {
    const float4* w4 = (const float4*)wg;
    float4* l4 = (float4*)wls;
    for (int i = t; i < NE * CD / 4; i += 256) l4[i] = w4[i];
  }
  __syncthreads();
  const int wave = t >> 6, lane = t & 63;
  const int gw = blockIdx.x * 4 + wave;
  const float4* wls4 = (const float4*)wls;
#pragma unroll
  for (int it = 0; it < 2; ++it) {
    const int n = gw * 2 + it;
    const float4* xr4 = (const float4*)(x + (size_t)n * CD);
    ushort4* xb4 = (ushort4*)(xb + (size_t)n * CD);
    double acc[NE] = {0, 0, 0, 0, 0, 0, 0, 0};
#pragma unroll
    for (int j = 0; j < 4; ++j) {
      const int idx = j * 64 + lane;
      const float4 xv = xr4[idx];
      ushort4 o;
      o.x = f2bf(xv.x); o.y = f2bf(xv.y); o.z = f2bf(xv.z); o.w = f2bf(xv.w);
      xb4[idx] = o;
#pragma unroll
      for (int e = 0; e < NE; ++e) {
        const float4 wv = wls4[e * 256 + idx];
        acc[e] += (double)xv.x * (double)wv.x + (double)xv.y * (double)wv.y
                + (double)xv.z * (double)wv.z + (double)xv.w * (double)wv.w;
      }
    }
#pragma unroll
    for (int s = 32; s >= 1; s >>= 1) {
#pragma unroll
      for (int e = 0; e < NE; ++e) acc[e] += __shfl_xor(acc[e], s, 64);
    }
    if (lane == 0) {
      int i1 = 0; double v1 = acc[0];
      for (int e = 1; e < NE; ++e) if (acc[e] > v1) { v1 = acc[e]; i1 = e; }
      int i2 = -1; double v2 = -1e300;
      for (int e = 0; e < NE; ++e) if (e != i1 && acc[e] > v2) { v2 = acc[e]; i2 = e; }
      float p0 = 1.0f / (1.0f + expf((float)(v2 - v1)));
      topidx[n * 2 + 0] = i1; topidx[n * 2 + 1] = i2;
      probs[n * 2 + 0] = p0; probs[n * 2 + 1] = 1.0f - p0;
    }
  }
}

// ---------------- per-block expert histograms ----------------
__global__ __launch_bounds__(256) void hist_k(const int* __restrict__ topidx, int* __restrict__ blkhist) {
  __shared__ int h[16];
  const int t = threadIdx.x;
  if (t < 16) h[t] = 0;
  __syncthreads();
  const int n = blockIdx.x * 256 + t;
  atomicAdd(&h[topidx[n * 2 + 0]], 1);
  atomicAdd(&h[8 + topidx[n * 2 + 1]], 1);
  __syncthreads();
  if (t < 16) blkhist[blockIdx.x * 16 + t] = h[t];
}

// ---------------- scan ----------------
__global__ void scan_k(const int* __restrict__ blkhist, int* __restrict__ blkoff, int* __restrict__ totals_cnt) {
  const int t = threadIdx.x;
  if (t < 16) {
    int s = 0;
    for (int b = 0; b < 64; ++b) { blkoff[b * 16 + t] = s; s += blkhist[b * 16 + t]; }
    totals_cnt[t] = s;
  }
  __syncthreads();
  if (t < 8) {
    int tot = totals_cnt[t] + totals_cnt[8 + t];
    totals_cnt[16 + t] = tot < CAP ? tot : CAP;
  }
}

// ---------------- ranks + slot_map scatter (slotmap[e][rank] = n*2+k) ----------------
__global__ __launch_bounds__(256) void rank_k(
    const int* __restrict__ topidx, const int* __restrict__ blkoff,
    const int* __restrict__ totals_cnt, int* __restrict__ ranks, int* __restrict__ slotmap) {
  __shared__ int wcnt[2][4][8];
  __shared__ int woff[2][4][8];
  const int t = threadIdx.x, wave = t >> 6, lane = t & 63;
  const int n = blockIdx.x * 256 + t;
  const int e1 = topidx[n * 2 + 0], e2 = topidx[n * 2 + 1];
  const unsigned long long lt = (1ull << lane) - 1ull;
  int pre1 = 0, pre2 = 0;
#pragma unroll
  for (int e = 0; e < 8; ++e) {
    unsigned long long m1 = __ballot(e1 == e);
    unsigned long long m2 = __ballot(e2 == e);
    if (e1 == e) pre1 = __popcll(m1 & lt);
    if (e2 == e) pre2 = __popcll(m2 & lt);
    if (lane == 0) { wcnt[0][wave][e] = __popcll(m1); wcnt[1][wave][e] = __popcll(m2); }
  }
  __syncthreads();
  if (t < 16) {
    int k = t >> 3, e = t & 7, s = 0;
    for (int w = 0; w < 4; ++w) { woff[k][w][e] = s; s += wcnt[k][w][e]; }
  }
  __syncthreads();
  int r1 = blkoff[blockIdx.x * 16 + e1] + woff[0][wave][e1] + pre1;
  int r2 = totals_cnt[e2] + blkoff[blockIdx.x * 16 + 8 + e2] + woff[1][wave][e2] + pre2;
  ranks[n * 2 + 0] = (r1 < CAP) ? r1 : -1;
  ranks[n * 2 + 1] = (r2 < CAP) ? r2 : -1;
  if (r1 < CAP) slotmap[e1 * CAP + r1] = n * 2 + 0;
  if (r2 < CAP) slotmap[e2 * CAP + r2] = n * 2 + 1;
}

// ---- shared mapping helper: live-tile compaction + chunked-XCD, nt fastest ----
template <int BM, int TN>
__device__ __forceinline__ bool map_tile(const int* cnt, int e_base, int n_le,
                                         int& le, int& mt, int& nt) {
  constexpr int TM = CAP / BM;
  int pref[9];
  int L = 0;
  for (int i = 0; i < n_le; ++i) {
    pref[i] = L;
    int lm = (cnt[e_base + i] + BM - 1) / BM;
    if (lm > TM) lm = TM;
    L += lm;
  }
  const int totalLive = L * TN;
  const int bid = blockIdx.x;
  if (bid >= totalLive) return false;
  const int q = totalLive >> 3, r = totalLive & 7;
  const int xcd = bid & 7, lin = bid >> 3;
  const int wid = (xcd < r ? xcd * (q + 1) : r * (q + 1) + (xcd - r) * q) + lin;
  const int pair = wid / TN;
  nt = wid % TN;                   // nt fastest: siblings share A-panel in XCD L2
  le = n_le - 1;
  for (int i = 1; i < n_le; ++i) if (pair < pref[i]) { le = i - 1; break; }
  mt = pair - pref[le];
  return true;
}

// ====== G1: 4-phase MFMA GEMM, BK=64, 2-slot dbuf, counted vmcnt, T2 swizzle ======
// R13 ledger (24 ds_read_b128/wave/tile). Proven R13/R14.
template <int BM, int KDIM, int NDIM, bool GATHER, bool RELU2>
__global__ __launch_bounds__(512) void gemm8p_k(
    const unsigned short* __restrict__ A, const unsigned short* __restrict__ Bt,
    unsigned short* __restrict__ Out, const int* __restrict__ slotmap,
    const int* __restrict__ cnt, int e_base, int n_le) {
  constexpr int BN = 256;
  constexpr int KT = KDIM / 64;
  constexpr int TN = NDIM / BN;
  constexpr int M_REP = BM / 32;
  constexpr int QM = M_REP / 2;
  constexpr int AL = BM / 128;
  constexpr int BL = 2;
  constexpr int V = AL + BL;

  __shared__ unsigned short lA[2][BM * 64];
  __shared__ unsigned short lB[2][BN * 64];

  int le, mt, nt;
  if (!map_tile<BM, TN>(cnt, e_base, n_le, le, mt, nt)) return;
  const int e = e_base + le;

  const int tid = threadIdx.x;
  const int wave = tid >> 6, lane = tid & 63;
  const int wr = wave >> 2, wc = wave & 3;
  const int l15 = lane & 15, l4 = lane >> 4;

  const unsigned short* sApt[2][AL];
  const unsigned short* sBpt[2][BL];
#pragma unroll
  for (int h = 0; h < 2; ++h) {
#pragma unroll
    for (int j = 0; j < AL; ++j) {
      const int lc = j * 512 + tid;
      const int lr = lc >> 3, pc = lc & 7;
      const int logc = pc ^ (lr & 7);
      const int rowT = h * (BM / 2) + lr;
      size_t grow;
      if (GATHER) {
        const int sv = slotmap[e * CAP + mt * BM + rowT];
        grow = (size_t)(sv < 0 ? 0 : (sv >> 1));
      } else {
        grow = (size_t)le * CAP + mt * BM + rowT;
      }
      sApt[h][j] = A + grow * KDIM + logc * 8;
    }
#pragma unroll
    for (int j = 0; j < BL; ++j) {
      const int lc = j * 512 + tid;
      const int lr = lc >> 3, pc = lc & 7;
      const int logc = pc ^ (lr & 7);
      sBpt[h][j] = Bt + ((size_t)le * NDIM + nt * BN + h * 128 + lr) * KDIM + logc * 8;
    }
  }

#define STAGE_A(sl, h, tt)                                                              \
  do { _Pragma("unroll") for (int j = 0; j < AL; ++j)                                   \
    g2lds16(sApt[h][j] + (size_t)(tt) * 64,                                             \
            &lA[sl][((h) * (BM / 2) * 8 + j * 512 + wave * 64) * 8]); } while (0)
#define STAGE_B(sl, h, tt)                                                              \
  do { _Pragma("unroll") for (int j = 0; j < BL; ++j)                                   \
    g2lds16(sBpt[h][j] + (size_t)(tt) * 64,                                             \
            &lB[sl][((h) * 128 * 8 + j * 512 + wave * 64) * 8]); } while (0)

  const int kidx0 = ((0 * 4 + l4) ^ (l15 & 7)) * 8;
  const int kidx1 = ((1 * 4 + l4) ^ (l15 & 7)) * 8;

#define RD_A(mh)                                                                        \
  do { _Pragma("unroll") for (int m = 0; m < QM; ++m) {                                 \
    const int row = (mh) * (BM / 2) + wr * (BM / 4) + m * 16 + l15;                     \
    aF[m][0] = *(const short8*)(bA + row * 64 + kidx0);                                 \
    aF[m][1] = *(const short8*)(bA + row * 64 + kidx1); } } while (0)
#define RD_B(DST, nh)                                                                   \
  do { _Pragma("unroll") for (int n = 0; n < 2; ++n) {                                  \
    const int row = (nh) * 128 + wc * 32 + n * 16 + l15;                                \
    DST[n][0] = *(const short8*)(bB + row * 64 + kidx0);                                \
    DST[n][1] = *(const short8*)(bB + row * 64 + kidx1); } } while (0)
#define LGK0()                                                                          \
  do { asm volatile("s_waitcnt lgkmcnt(0)" ::: "memory");                               \
       __builtin_amdgcn_sched_barrier(0); } while (0)
#define MF(BARR, mh, nh)                                                                \
  do { __builtin_amdgcn_s_setprio(1);                                                   \
    _Pragma("unroll") for (int m = 0; m < QM; ++m)                                      \
      _Pragma("unroll") for (int n = 0; n < 2; ++n) {                                   \
        acc[(mh) * QM + m][(nh) * 2 + n] = __builtin_amdgcn_mfma_f32_16x16x32_bf16(     \
            aF[m][0], BARR[n][0], acc[(mh) * QM + m][(nh) * 2 + n], 0, 0, 0);           \
        acc[(mh) * QM + m][(nh) * 2 + n] = __builtin_amdgcn_mfma_f32_16x16x32_bf16(     \
            aF[m][1], BARR[n][1], acc[(mh) * QM + m][(nh) * 2 + n], 0, 0, 0); }         \
    __builtin_amdgcn_s_setprio(0); } while (0)
#define VMC_V()  do { if constexpr (V == 4) asm volatile("s_waitcnt vmcnt(4)" ::: "memory"); \
                      else asm volatile("s_waitcnt vmcnt(3)" ::: "memory"); } while (0)
#define VMC_2()  asm volatile("s_waitcnt vmcnt(2)" ::: "memory")
#define VMC_0()  asm volatile("s_waitcnt vmcnt(0)" ::: "memory")
#define BAR()    do { __builtin_amdgcn_s_barrier(); asm volatile("" ::: "memory"); } while (0)

  f32x4 acc[M_REP][4] = {};
  short8 aF[QM][2], bF0[2][2], bF1[2][2];

  STAGE_A(0, 0, 0); STAGE_B(0, 0, 0); STAGE_B(0, 1, 0); STAGE_A(0, 1, 0);
  VMC_V();
  BAR();

  int s = 0;
  for (int t = 0; t < KT; ++t) {
    const int s2 = s ^ 1;
    const unsigned short* bA = &lA[s][0];
    const unsigned short* bB = &lB[s][0];
    const bool more = (t + 1 < KT);

    RD_A(0); RD_B(bF0, 0);
    if (more) { STAGE_A(s2, 0, t + 1); VMC_V(); } else { VMC_2(); }
    LGK0();
    MF(bF0, 0, 0);
    BAR();
    RD_B(bF1, 1);
    if (more) { STAGE_B(s2, 0, t + 1); VMC_V(); } else { VMC_0(); }
    LGK0();
    MF(bF1, 0, 1);
    BAR();
    RD_A(1);
    if (more) STAGE_B(s2, 1, t + 1);
    LGK0();
    MF(bF1, 1, 1);
    if (more) { STAGE_A(s2, 1, t + 1); VMC_V(); }
    MF(bF0, 1, 0);
    if (more) BAR();
    s = s2;
  }

  const size_t rowb = (size_t)le * CAP + mt * BM;
  const int colb = nt * BN;
#pragma unroll
  for (int i = 0; i < M_REP; ++i) {
    const int mh = i / QM, m = i % QM;
#pragma unroll
    for (int j = 0; j < 4; ++j) {
      const int nh = j / 2, n = j % 2;
#pragma unroll
      for (int rr = 0; rr < 4; ++rr) {
        float v = acc[i][j][rr];
        if (RELU2) { v = fmaxf(v, 0.0f); v = v * v; }
        const size_t orow = rowb + mh * (BM / 2) + wr * (BM / 4) + m * 16 + l4 * 4 + rr;
        Out[orow * NDIM + colb + nh * 128 + wc * 32 + n * 16 + l15] = f2bf(v);
      }
    }
  }
#undef STAGE_A
#undef STAGE_B
#undef RD_A
#undef RD_B
#undef LGK0
#undef MF
#undef VMC_V
#undef VMC_2
#undef VMC_0
#undef BAR
}

// ====== G2: pipelined MFMA GEMM (R5/R11-proven): BK=32, 3-slot LDS, counted vmcnt ======
// R15 SCATTER epilogue: PLAIN STORES, no atomics. Entries (token,k) are globally unique
// per k (a token's two experts are distinct), so k=0 contributions -> outp (f32) and
// k=1 contributions -> out2 (bf16) are collision-free. sum_k merges with rank masks.
template <int WM, int WN, int BM, int BN, int KDIM, int NDIM, bool GATHER, bool RELU2, bool SCATTER>
__global__ __launch_bounds__(WM * WN * 64) void gemm8_k(
    const unsigned short* __restrict__ A, const unsigned short* __restrict__ Bt,
    unsigned short* __restrict__ Out, const int* __restrict__ slotmap,
    const int* __restrict__ cnt, int e_base, int n_le,
    const float* __restrict__ probs, float* __restrict__ outp,
    unsigned short* __restrict__ out2) {
  constexpr int THREADS = WM * WN * 64;
  constexpr int KT = KDIM / 32;
  constexpr int TN = NDIM / BN;
  constexpr int M_REP = BM / WM / 16;
  constexpr int N_REP = BN / WN / 16;
  constexpr int MH = M_REP / 2;
  constexpr int ALOADS = BM * 4 / THREADS;
  constexpr int BLOADS = BN * 4 / THREADS;
  static_assert(ALOADS + BLOADS == 4, "vmcnt literal assumes 4 loads/wave/tile");

  __shared__ unsigned short lA[3][BM * 32];
  __shared__ unsigned short lB[3][BN * 32];

  int le, mt, nt;
  if (!map_tile<BM, TN>(cnt, e_base, n_le, le, mt, nt)) return;
  const int e = e_base + le;

  const int tid = threadIdx.x;
  const int wave = tid >> 6, lane = tid & 63;
  const int wr = wave / WN, wc = wave % WN;
  const int l15 = lane & 15, l4 = lane >> 4;

  const unsigned short* pA[ALOADS];
  const unsigned short* pB[BLOADS];
#pragma unroll
  for (int j = 0; j < ALOADS; ++j) {
    const int ci = j * THREADS + tid;
    const int row = ci >> 2, cst = ci & 3;
    const int csrc = cst ^ ((row >> 1) & 3);
    size_t grow;
    if (GATHER) {
      const int sv = slotmap[e * CAP + mt * BM + row];
      grow = (size_t)(sv < 0 ? 0 : (sv >> 1));
    } else {
      grow = (size_t)le * CAP + mt * BM + row;
    }
    pA[j] = A + grow * KDIM + csrc * 8;
  }
#pragma unroll
  for (int j = 0; j < BLOADS; ++j) {
    const int ci = j * THREADS + tid;
    const int row = ci >> 2, cst = ci & 3;
    const int csrc = cst ^ ((row >> 1) & 3);
    pB[j] = Bt + ((size_t)le * NDIM + nt * BN + row) * KDIM + csrc * 8;
  }

  const int ksw = (l4 ^ ((l15 >> 1) & 3)) * 8;
  int aOff[M_REP], bOff[N_REP];
#pragma unroll
  for (int m = 0; m < M_REP; ++m)
    aOff[m] = (wr * (BM / WM) + m * 16 + l15) * 32 + ksw;
#pragma unroll
  for (int n = 0; n < N_REP; ++n)
    bOff[n] = (wc * (BN / WN) + n * 16 + l15) * 32 + ksw;

  f32x4 acc[M_REP][N_REP] = {};

#pragma unroll
  for (int kt = 0; kt < 2; ++kt) {
#pragma unroll
    for (int j = 0; j < ALOADS; ++j)
      g2lds16(pA[j] + kt * 32, &lA[kt][(j * THREADS + wave * 64) * 8]);
#pragma unroll
    for (int j = 0; j < BLOADS; ++j)
      g2lds16(pB[j] + kt * 32, &lB[kt][(j * THREADS + wave * 64) * 8]);
  }

  for (int t = 0; t < KT; ++t) {
    if (t < KT - 1) asm volatile("s_waitcnt vmcnt(4)" ::: "memory");
    else            asm volatile("s_waitcnt vmcnt(0)" ::: "memory");
    __builtin_amdgcn_s_barrier();
    asm volatile("" ::: "memory");

    const int s = t % 3, s2 = (t + 2) % 3;
    const unsigned short* sA = &lA[s][0];
    const unsigned short* sB = &lB[s][0];
    const bool pf = (t + 2 < KT);

    short8 aF[MH], bF[N_REP];
#pragma unroll
    for (int m = 0; m < MH; ++m) aF[m] = *(const short8*)(sA + aOff[m]);
#pragma unroll
    for (int n = 0; n < N_REP; ++n) bF[n] = *(const short8*)(sB + bOff[n]);
    if (pf) {
#pragma unroll
      for (int j = 0; j < ALOADS; ++j)
        g2lds16(pA[j] + (t + 2) * 32, &lA[s2][(j * THREADS + wave * 64) * 8]);
    }
    asm volatile("s_waitcnt lgkmcnt(0)" ::: "memory");
    __builtin_amdgcn_sched_barrier(0);
    __builtin_amdgcn_s_setprio(1);
#pragma unroll
    for (int m = 0; m < MH; ++m)
#pragma unroll
      for (int n = 0; n < N_REP; ++n)
        acc[m][n] = __builtin_amdgcn_mfma_f32_16x16x32_bf16(aF[m], bF[n], acc[m][n], 0, 0, 0);
    __builtin_amdgcn_s_setprio(0);

    short8 aG[MH];
#pragma unroll
    for (int m = 0; m < MH; ++m) aG[m] = *(const short8*)(sA + aOff[MH + m]);
    if (pf) {
#pragma unroll
      for (int j = 0; j < BLOADS; ++j)
        g2lds16(pB[j] + (t + 2) * 32, &lB[s2][(j * THREADS + wave * 64) * 8]);
    }
    asm volatile("s_waitcnt lgkmcnt(0)" ::: "memory");
    __builtin_amdgcn_sched_barrier(0);
    __builtin_amdgcn_s_setprio(1);
#pragma unroll
    for (int m = 0; m < MH; ++m)
#pragma unroll
      for (int n = 0; n < N_REP; ++n)
        acc[MH + m][n] = __builtin_amdgcn_mfma_f32_16x16x32_bf16(aG[m], bF[n], acc[MH + m][n], 0, 0, 0);
    __builtin_amdgcn_s_setprio(0);
  }

  if (SCATTER) {
    const int colb = nt * BN + wc * (BN / WN);
#pragma unroll
    for (int m = 0; m < M_REP; ++m) {
#pragma unroll
      for (int rr = 0; rr < 4; ++rr) {
        const int rl = mt * BM + wr * (BM / WM) + m * 16 + l4 * 4 + rr;
        const int sv = slotmap[e * CAP + rl];
        if (sv < 0) continue;
        const float p = probs[sv];
        const size_t tok = (size_t)(sv >> 1);
        if (sv & 1) {
          unsigned short* ob = out2 + tok * CD + colb + l15;
#pragma unroll
          for (int n = 0; n < N_REP; ++n) ob[n * 16] = f2bf(p * acc[m][n][rr]);
        } else {
          float* ob = outp + tok * CD + colb + l15;
#pragma unroll
          for (int n = 0; n < N_REP; ++n) ob[n * 16] = p * acc[m][n][rr];
        }
      }
    }
  } else {
    const size_t rowb = (size_t)le * CAP + mt * BM + wr * (BM / WM);
    const int colb = nt * BN + wc * (BN / WN);
#pragma unroll
    for (int m = 0; m < M_REP; ++m)
#pragma unroll
      for (int n = 0; n < N_REP; ++n)
#pragma unroll
        for (int rr = 0; rr < 4; ++rr) {
          float v = acc[m][n][rr];
          if (RELU2) { v = fmaxf(v, 0.0f); v = v * v; }
          Out[(rowb + m * 16 + l4 * 4 + rr) * NDIM + colb + n * 16 + l15] = f2bf(v);
        }
  }
}

// ---------------- sum: out[n] = mask(r1)*out[n] + mask(r2)*bf2f(out2[n]) ----------------
__global__ __launch_bounds__(256) void sum_k(
    const unsigned short* __restrict__ out2, const int* __restrict__ ranks,
    float* __restrict__ out) {
  const int n = blockIdx.x, t = threadIdx.x;
  const int c = t * 4;
  const int r1 = ranks[n * 2 + 0], r2 = ranks[n * 2 + 1];
  float4 v = make_float4(0.f, 0.f, 0.f, 0.f);
  if (r1 >= 0) v = *reinterpret_cast<const float4*>(out + (size_t)n * CD + c);
  if (r2 >= 0) {
    const ushort4 u = *(const ushort4*)(out2 + (size_t)n * CD + c);
    v.x += bf2f(u.x); v.y += bf2f(u.y); v.z += bf2f(u.z); v.w += bf2f(u.w);
  }
  *reinterpret_cast<float4*>(out + (size_t)n * CD + c) = v;
}

// ---------------- launch ----------------
extern "C" void kernel_launch(void* const* d_in, const int* in_sizes, int n_in,
                              void* d_out, int out_size, void* d_ws, size_t ws_size,
                              hipStream_t stream) {
  const float* x = (const float*)d_in[0];
  const float* wg = (const float*)d_in[1];
  const float* cfc = (const float*)d_in[2];
  const float* cproj = (const float*)d_in[3];
  float* out = (float*)d_out;
  char* ws = (char*)d_ws;
  (void)in_sizes; (void)n_in; (void)out_size;

  const size_t W1SZ = (size_t)FCD * CD * 2;    // 8 MB per expert weight (bf16, transposed)
  const size_t HSZ  = (size_t)CAP * FCD * 2;   // 40 MB per expert hidden
  const size_t O2SZ = (size_t)NT * CD * 2;     // 32 MB k=1 contribution buffer (bf16)

  size_t off = 0;
  auto alloc = [&](size_t bytes) { size_t o = off; off = (off + bytes + 255) & ~(size_t)255; return o; };
  unsigned short* XB = (unsigned short*)(ws + alloc((size_t)NT * CD * 2));   // 32 MB
  int* TOPIDX  = (int*)(ws + alloc((size_t)NT * 2 * 4));
  float* PROBS = (float*)(ws + alloc((size_t)NT * 2 * 4));
  int* RANKS   = (int*)(ws + alloc((size_t)NT * 2 * 4));
  int* SLOTMAP = (int*)(ws + alloc((size_t)NE * CAP * 4));
  int* BLKHIST = (int*)(ws + alloc(64 * 16 * 4));
  int* BLKOFF  = (int*)(ws + alloc(64 * 16 * 4));
  int* TOTALS  = (int*)(ws + alloc(256));
  const size_t shared_end = off;
  int* CNT = TOTALS + 16;

  size_t woff = shared_end;
  auto walloc = [&](size_t bytes) { size_t o = woff; woff = (woff + bytes + 255) & ~(size_t)255; return o; };
  const size_t oCFCT   = walloc(NE * W1SZ);   // 64 MB
  const size_t oCPROJT = walloc(NE * W1SZ);   // 64 MB
  const size_t weights_end = woff;

  // pick largest EG in {8,4,2,1}. At EG=8, OUT2 aliases XB (XB dead after the single G1
  // dispatch; router rewrites XB every launch -> replay-deterministic). Else OUT2 separate.
  int EG = 0;
  bool aliasO2 = false;
  for (int g = 8; g >= 1; g >>= 1) {
    size_t need = weights_end + (size_t)g * HSZ + 512 + (g == 8 ? 0 : O2SZ + 512);
    if (ws_size >= need) { EG = g; aliasO2 = (g == 8); break; }
  }
  if (EG == 0) {
    fill_zero_f32x4_k<<<(NT * CD / 4 + 255) / 256, 256, 0, stream>>>((float4*)out, (size_t)NT * CD / 4);
    return;   // controlled failure instead of memory fault
  }

  // prologue
  fill_i32_k<<<(NE * CAP + 255) / 256, 256, 0, stream>>>(SLOTMAP, -1, NE * CAP);
  router_k<<<2048, 256, 0, stream>>>(x, wg, XB, TOPIDX, PROBS);
  hist_k<<<64, 256, 0, stream>>>(TOPIDX, BLKHIST);
  scan_k<<<1, 64, 0, stream>>>(BLKHIST, BLKOFF, TOTALS);
  rank_k<<<64, 256, 0, stream>>>(TOPIDX, BLKOFF, TOTALS, RANKS, SLOTMAP);

  unsigned short* CFCT   = (unsigned short*)(ws + oCFCT);
  unsigned short* CPROJT = (unsigned short*)(ws + oCPROJT);
  transpose_bf16_k<<<dim3(FCD / 64, CD / 64, NE), 256, 0, stream>>>(cfc, CFCT, CD, FCD);
  transpose_bf16_k<<<dim3(CD / 64, FCD / 64, NE), 256, 0, stream>>>(cproj, CPROJT, FCD, CD);

  unsigned short* H = (unsigned short*)(ws + weights_end);
  unsigned short* OUT2 = aliasO2 ? XB
      : (unsigned short*)(ws + ((weights_end + (size_t)EG * HSZ + 255) & ~(size_t)255));

  for (int g = 0; g < NE / EG; ++g) {
    const int eb = g * EG;
    // G1: 256x256, 8 waves, 4-phase pipeline (R13 ledger) + compaction
    gemm8p_k<256, CD, FCD, true, true>
        <<<EG * (CAP / 256) * (FCD / 256), 512, 0, stream>>>(
        XB, CFCT + (size_t)eb * FCD * CD, H, SLOTMAP, CNT, eb, EG);
    // G2: 128x128, 4 waves, 3-slot BK32 + compaction + race-free dual-buffer scatter
    gemm8_k<2, 2, 128, 128, FCD, CD, false, false, true>
        <<<EG * (CAP / 128) * (CD / 128), 256, 0, stream>>>(
        H, CPROJT + (size_t)eb * CD * FCD, nullptr, SLOTMAP, CNT, eb, EG, PROBS, out, OUT2);
  }
  sum_k<<<NT, 256, 0, stream>>>(OUT2, RANKS, out);
}